// Round 8
// baseline (777.175 us; speedup 1.0000x reference)
//
#include <hip/hip_runtime.h>
#include <math.h>

#define SEQ    4096
#define NFFT   8192
#define DMODEL 1024
#define ORDER  64
#define CT     512
#define MLPT   256

typedef float2 cf;

// LDS swizzle on complex index: XOR bits [3:1] with bits [6:4].
// Preserves even pairs (bit 0) and float4 (16 B) alignment.
#define ZI(c) ((c) ^ ((((c) >> 4) & 7) << 1))

__device__ __forceinline__ cf cadd(cf a, cf b) { return make_float2(a.x + b.x, a.y + b.y); }
__device__ __forceinline__ cf csub(cf a, cf b) { return make_float2(a.x - b.x, a.y - b.y); }
__device__ __forceinline__ cf cmul(cf a, cf b) { return make_float2(a.x * b.x - a.y * b.y, a.x * b.y + a.y * b.x); }
__device__ __forceinline__ cf cmulj(cf a, cf b) { return make_float2(a.x * b.x + a.y * b.y, a.y * b.x - a.x * b.y); } // a*conj(b)

#define RT2 0.70710678118654752f
#define C16 0.92387953251128676f
#define S16 0.38268343236508977f

template<bool INV>
__device__ __forceinline__ cf cmulc(cf a, float cx, float sy) {
    if (!INV) return make_float2(a.x * cx + a.y * sy, a.y * cx - a.x * sy);
    else      return make_float2(a.x * cx - a.y * sy, a.y * cx + a.x * sy);
}
template<bool INV> __device__ __forceinline__ cf tw8_1(cf d) {
    if (!INV) return make_float2(RT2 * (d.x + d.y), RT2 * (d.y - d.x));
    else      return make_float2(RT2 * (d.x - d.y), RT2 * (d.y + d.x));
}
template<bool INV> __device__ __forceinline__ cf tw8_2(cf d) {
    if (!INV) return make_float2(d.y, -d.x);
    else      return make_float2(-d.y, d.x);
}
template<bool INV> __device__ __forceinline__ cf tw8_3(cf d) {
    if (!INV) return make_float2(RT2 * (d.y - d.x), -RT2 * (d.x + d.y));
    else      return make_float2(-RT2 * (d.x + d.y), RT2 * (d.x - d.y));
}

template<bool INV>
__device__ __forceinline__ void dft4(cf& x0, cf& x1, cf& x2, cf& x3) {
    cf A = cadd(x0, x2), B = csub(x0, x2);
    cf C = cadd(x1, x3), D = csub(x1, x3);
    x0 = cadd(A, C); x2 = csub(A, C);
    if (!INV) { x1 = make_float2(B.x + D.y, B.y - D.x); x3 = make_float2(B.x - D.y, B.y + D.x); }
    else      { x1 = make_float2(B.x - D.y, B.y + D.x); x3 = make_float2(B.x + D.y, B.y - D.x); }
}

template<bool INV>
__device__ __forceinline__ void dft8(cf v[8]) {
    cf s0 = cadd(v[0], v[4]), s1 = cadd(v[1], v[5]), s2 = cadd(v[2], v[6]), s3 = cadd(v[3], v[7]);
    cf d0 = csub(v[0], v[4]), d1 = csub(v[1], v[5]), d2 = csub(v[2], v[6]), d3 = csub(v[3], v[7]);
    cf t1 = tw8_1<INV>(d1), t2 = tw8_2<INV>(d2), t3 = tw8_3<INV>(d3);
    dft4<INV>(s0, s1, s2, s3);
    dft4<INV>(d0, t1, t2, t3);
    v[0] = s0; v[2] = s1; v[4] = s2; v[6] = s3;
    v[1] = d0; v[3] = t1; v[5] = t2; v[7] = t3;
}

template<bool INV>
__device__ __forceinline__ void dft16(cf v[16]) {
    cf s[8], t[8];
    #pragma unroll
    for (int m = 0; m < 8; m++) { s[m] = cadd(v[m], v[m + 8]); t[m] = csub(v[m], v[m + 8]); }
    t[1] = cmulc<INV>(t[1], C16, S16);
    t[2] = tw8_1<INV>(t[2]);
    t[3] = cmulc<INV>(t[3], S16, C16);
    t[4] = tw8_2<INV>(t[4]);
    t[5] = cmulc<INV>(t[5], -S16, C16);
    t[6] = tw8_3<INV>(t[6]);
    t[7] = cmulc<INV>(t[7], -C16, S16);
    dft8<INV>(s); dft8<INV>(t);
    #pragma unroll
    for (int k = 0; k < 8; k++) { v[2 * k] = s[k]; v[2 * k + 1] = t[k]; }
}

// Radix-8 stage for the 8192 machinery, pair-of-butterflies per thread (b128).
// Twiddles loaded directly from LUT: W^k = tw[S*j*k] (all indices < 8192).
template<int L, int S, bool FIRST>
__device__ __forceinline__ void stage_fwd(float2* z, const cf* __restrict__ tw) {
    int t = threadIdx.x;
    int j0 = 2 * (t & (L / 2 - 1));
    int base = (t / (L / 2)) * (8 * L);
    int c0 = base + j0;
    cf a[8], b[8];
    #pragma unroll
    for (int k = 0; k < 8; k++) {
        if (FIRST && k >= 4) { a[k] = make_float2(0.f, 0.f); b[k] = a[k]; }
        else {
            float4 p = *(const float4*)&z[ZI(c0 + k * L)];
            a[k] = make_float2(p.x, p.y); b[k] = make_float2(p.z, p.w);
        }
    }
    dft8<false>(a); dft8<false>(b);
    #pragma unroll
    for (int k = 1; k < 8; k++) {
        a[k] = cmul(a[k], tw[S * j0 * k]);
        b[k] = cmul(b[k], tw[S * (j0 + 1) * k]);
    }
    #pragma unroll
    for (int k = 0; k < 8; k++)
        *(float4*)&z[ZI(c0 + k * L)] = make_float4(a[k].x, a[k].y, b[k].x, b[k].y);
    __syncthreads();
}

template<int L, int S>
__device__ __forceinline__ void stage_inv(float2* z, const cf* __restrict__ tw) {
    int t = threadIdx.x;
    int j0 = 2 * (t & (L / 2 - 1));
    int base = (t / (L / 2)) * (8 * L);
    int c0 = base + j0;
    cf a[8], b[8];
    #pragma unroll
    for (int k = 0; k < 8; k++) {
        float4 p = *(const float4*)&z[ZI(c0 + k * L)];
        a[k] = make_float2(p.x, p.y); b[k] = make_float2(p.z, p.w);
    }
    #pragma unroll
    for (int k = 1; k < 8; k++) {
        a[k] = cmulj(a[k], tw[S * j0 * k]);
        b[k] = cmulj(b[k], tw[S * (j0 + 1) * k]);
    }
    dft8<true>(a); dft8<true>(b);
    #pragma unroll
    for (int k = 0; k < 8; k++)
        *(float4*)&z[ZI(c0 + k * L)] = make_float4(a[k].x, a[k].y, b[k].x, b[k].y);
    __syncthreads();
}

// Radix-8 stage for the 4096-pt K-FFT: one butterfly per thread (b64 LDS ops).
template<int L, int S, bool FIRST>
__device__ __forceinline__ void stage4k_fwd(float2* z, const cf* __restrict__ tw) {
    int t = threadIdx.x;                 // 512 butterflies, one per thread
    int j = t & (L - 1);
    int c0 = (t / L) * (8 * L) + j;
    cf a[8];
    #pragma unroll
    for (int k = 0; k < 8; k++) {
        if (FIRST && k >= 4) a[k] = make_float2(0.f, 0.f);
        else                 a[k] = z[ZI(c0 + k * L)];
    }
    dft8<false>(a);
    #pragma unroll
    for (int k = 1; k < 8; k++) a[k] = cmul(a[k], tw[S * j * k]);
    #pragma unroll
    for (int k = 0; k < 8; k++) z[ZI(c0 + k * L)] = a[k];
    __syncthreads();
}

__device__ __forceinline__ int REV3(int u) { // 9-bit base-8 digit reverse
    return ((u & 7) << 6) | (u & 56) | ((u >> 6) & 7);
}

// ---------------------------------------------------------------------------
// MLP hidden states (Ht[o][l]) + twiddle table init (blocks 0..31).
// ---------------------------------------------------------------------------
__global__ void mlp_kernel(const float* __restrict__ W1, const float* __restrict__ b1,
                           const float* __restrict__ W2, const float* __restrict__ b2,
                           const float* __restrict__ W3, const float* __restrict__ b3,
                           const float* __restrict__ freq, float* __restrict__ Ht,
                           cf* __restrict__ tw) {
    if (blockIdx.x < NFFT / MLPT) {
        int j = blockIdx.x * MLPT + threadIdx.x;
        double ang = (2.0 * M_PI / (double)NFFT) * (double)j;
        tw[j] = make_float2((float)cos(ang), (float)(-sin(ang)));
    }

    int o = threadIdx.x & 63;
    int p = threadIdx.x >> 6;
    int l = blockIdx.x * 4 + p;
    __shared__ float hs[4][ORDER];

    float t   = (float)l / 4095.0f;
    float ang = 1e-4f * (float)(2.0 * M_PI) * (float)l / 4096.0f;
    float z0 = t, z1 = cosf(ang), z2 = -sinf(ang);
    float fo = freq[o];

    float a = z0 * W1[o] + z1 * W1[ORDER + o] + z2 * W1[2 * ORDER + o] + b1[o];
    hs[p][o] = sinf(fo * a);
    __syncthreads();

    a = b2[o];
    #pragma unroll
    for (int i = 0; i < ORDER; i++) a += hs[p][i] * W2[i * ORDER + o];
    float h2 = sinf(fo * a);
    __syncthreads();
    hs[p][o] = h2;
    __syncthreads();

    a = b3[o];
    #pragma unroll
    for (int i = 0; i < ORDER; i++) a += hs[p][i] * W3[i * ORDER + o];
    Ht[o * SEQ + l] = sinf(fo * a);
}

// ---------------------------------------------------------------------------
// kgen2: tiled matmul + modulation: kfil[d][l] = (Ht^T Wout)[l][d] * exp(-t_l*delta_d)
// ---------------------------------------------------------------------------
__global__ __launch_bounds__(MLPT) void kgen2_kernel(const float* __restrict__ Wout,
                                                     const float* __restrict__ Ht,
                                                     float* __restrict__ kfil) {
    __shared__ float Hs[ORDER][68];
    __shared__ float Ws[ORDER][68];
    int t  = threadIdx.x;
    int dt = blockIdx.x & 15, lt = blockIdx.x >> 4;

    #pragma unroll
    for (int r = 0; r < 4; r++) {
        int idx = t + 256 * r;
        int o = idx >> 4, c4 = (idx & 15) * 4;
        *(float4*)&Hs[o][c4] = *(const float4*)&Ht[o * SEQ + lt * 64 + c4];
        *(float4*)&Ws[o][c4] = *(const float4*)&Wout[o * DMODEL + dt * 64 + c4];
    }
    __syncthreads();

    int lq = (t & 15) * 4;
    int dq = (t >> 4) * 4;
    float acc[4][4] = {{0.f}};
    #pragma unroll 8
    for (int o = 0; o < ORDER; o++) {
        float4 h = *(float4*)&Hs[o][lq];
        float4 w = *(float4*)&Ws[o][dq];
        acc[0][0] += w.x * h.x; acc[0][1] += w.x * h.y; acc[0][2] += w.x * h.z; acc[0][3] += w.x * h.w;
        acc[1][0] += w.y * h.x; acc[1][1] += w.y * h.y; acc[1][2] += w.y * h.z; acc[1][3] += w.y * h.w;
        acc[2][0] += w.z * h.x; acc[2][1] += w.z * h.y; acc[2][2] += w.z * h.z; acc[2][3] += w.z * h.w;
        acc[3][0] += w.w * h.x; acc[3][1] += w.w * h.y; acc[3][2] += w.w * h.z; acc[3][3] += w.w * h.w;
    }

    const float MIN_D = -3.0701134573253944f;   // log(.01)/1.5
    const float MAX_D = -15.350567286626971f;   // log(.01)/0.3
    int l0 = lt * 64 + lq;
    #pragma unroll
    for (int di = 0; di < 4; di++) {
        int d = dt * 64 + dq + di;
        float delta = fabsf(MIN_D + (MAX_D - MIN_D) * (float)d / 1023.0f);
        float4 o4;
        o4.x = acc[di][0] * expf(-((float)(l0 + 0) / 4095.0f) * delta);
        o4.y = acc[di][1] * expf(-((float)(l0 + 1) / 4095.0f) * delta);
        o4.z = acc[di][2] * expf(-((float)(l0 + 2) / 4095.0f) * delta);
        o4.w = acc[di][3] * expf(-((float)(l0 + 3) / 4095.0f) * delta);
        *(float4*)&kfil[(size_t)d * SEQ + l0] = o4;
    }
}

// ---------------------------------------------------------------------------
// Fused conv: per-channel WG. Phase K: packed 4096-pt FFT of kfil[d] +
// in-register untangle to kv[16] (bins F_i = REV3(t) + 512 i, *1/8192).
// Then 4 batch-pair convolutions (8192 machinery) with kv in registers.
// ---------------------------------------------------------------------------
__global__ __launch_bounds__(CT, 4) void conv_kernel(const float* __restrict__ x,
                                                     const float* __restrict__ bias,
                                                     const float* __restrict__ kfil,
                                                     const cf* __restrict__ tw,
                                                     float* __restrict__ out) {
    int d = blockIdx.x;
    int t = threadIdx.x;

    __shared__ __align__(16) float2 z[NFFT];

    // ---- Phase K: pack c[n] = k[2n] + i k[2n+1] (2048 live, rest zero) ----
    const float4* kf4 = (const float4*)(kfil + (size_t)d * SEQ);
    #pragma unroll
    for (int mm = 0; mm < 2; mm++) {
        int q = t + 512 * mm;                 // float4 q = complex pair (2q, 2q+1)
        *(float4*)&z[ZI(2 * q)] = kf4[q];
    }
    __syncthreads();

    stage4k_fwd<512, 2, true>(z, tw);
    stage4k_fwd<64, 16, false>(z, tw);
    stage4k_fwd<8, 128, false>(z, tw);

    // final contiguous dft8: own block kept in registers, published for partner
    cf own[8];
    #pragma unroll
    for (int i = 0; i < 4; i++) {
        float4 p = *(const float4*)&z[ZI(8 * t + 2 * i)];
        own[2 * i] = make_float2(p.x, p.y); own[2 * i + 1] = make_float2(p.z, p.w);
    }
    dft8<false>(own);
    #pragma unroll
    for (int i = 0; i < 4; i++)
        *(float4*)&z[ZI(8 * t + 2 * i)] = make_float4(own[2 * i].x, own[2 * i].y,
                                                      own[2 * i + 1].x, own[2 * i + 1].y);
    __syncthreads();

    // untangle rfft bins into kv[16]; kv[i] = K[REV3(t) + 512 i] / 8192
    cf kv[16];
    {
        const float sc = 1.0f / (float)NFFT;
        int r = REV3(t);
        if (r == 0) {                         // t == 0: self-paired bins 512m
            #pragma unroll
            for (int m = 0; m <= 8; m++) {
                cf Cf = own[m & 7], Cg = own[(8 - m) & 7];
                cf A = make_float2(0.5f * (Cf.x + Cg.x), 0.5f * (Cf.y - Cg.y));
                cf B = make_float2(Cf.x - Cg.x, Cf.y + Cg.y);
                cf W = tw[512 * m];
                cf U = make_float2(0.5f * (W.x * B.x - W.y * B.y),
                                   0.5f * (W.x * B.y + W.y * B.x));
                kv[m & 15] = make_float2(sc * (A.x + U.y), sc * (A.y - U.x));
            }
            #pragma unroll
            for (int i = 9; i < 16; i++)
                kv[i] = make_float2(kv[16 - i].x, -kv[16 - i].y);
        } else {
            int bp = REV3(512 - r);           // partner block index
            cf part[8];
            #pragma unroll
            for (int i = 0; i < 4; i++) {
                float4 p = *(const float4*)&z[ZI(8 * bp + 2 * i)];
                part[2 * i] = make_float2(p.x, p.y); part[2 * i + 1] = make_float2(p.z, p.w);
            }
            #pragma unroll
            for (int i = 0; i < 8; i++) {     // F = r + 512 i  (< 4096)
                cf Cf = own[i], Cg = part[7 - i];
                cf A = make_float2(0.5f * (Cf.x + Cg.x), 0.5f * (Cf.y - Cg.y));
                cf B = make_float2(Cf.x - Cg.x, Cf.y + Cg.y);
                cf W = tw[r + 512 * i];
                cf U = make_float2(0.5f * (W.x * B.x - W.y * B.y),
                                   0.5f * (W.x * B.y + W.y * B.x));
                kv[i] = make_float2(sc * (A.x + U.y), sc * (A.y - U.x));
            }
            #pragma unroll
            for (int i = 8; i < 16; i++) {    // F >= 4096: K[F] = conj(K[8192-F])
                cf Cf = part[15 - i], Cg = own[i - 8];
                cf A = make_float2(0.5f * (Cf.x + Cg.x), 0.5f * (Cf.y - Cg.y));
                cf B = make_float2(Cf.x - Cg.x, Cf.y + Cg.y);
                cf W = tw[(512 - r) + 512 * (15 - i)];
                cf U = make_float2(0.5f * (W.x * B.x - W.y * B.y),
                                   0.5f * (W.x * B.y + W.y * B.x));
                kv[i] = make_float2(sc * (A.x + U.y), -sc * (A.y - U.x));
            }
        }
    }

    float bd = bias[d];

    // ---- Pair loop: z = xa + i*xb -> FFT -> *kv -> IFFT -> epilogue ----
    for (int pair = 0; pair < 4; ++pair) {
        const float2* xa2 = (const float2*)(x + ((size_t)(2 * pair) * DMODEL + d) * SEQ);
        const float2* xb2 = (const float2*)(x + ((size_t)(2 * pair + 1) * DMODEL + d) * SEQ);

        float2 ra[4], rb[4];
        #pragma unroll
        for (int m = 0; m < 4; m++) {         // issue loads before barrier
            int s = t + 512 * m;
            ra[m] = xa2[s]; rb[m] = xb2[s];
        }
        __syncthreads();                      // prior phase's z reads done (WAR)
        #pragma unroll
        for (int m = 0; m < 4; m++) {
            int s = t + 512 * m;
            *(float4*)&z[ZI(2 * s)] = make_float4(ra[m].x, rb[m].x, ra[m].y, rb[m].y);
        }
        __syncthreads();

        stage_fwd<1024, 1, true>(z, tw);
        stage_fwd<128, 8, false>(z, tw);
        stage_fwd<16, 64, false>(z, tw);

        cf v[16];
        int c0 = 16 * t;
        #pragma unroll
        for (int i = 0; i < 8; i++) {
            float4 p = *(const float4*)&z[ZI(c0 + 2 * i)];
            v[2 * i] = make_float2(p.x, p.y); v[2 * i + 1] = make_float2(p.z, p.w);
        }
        dft16<false>(v);
        #pragma unroll
        for (int i = 0; i < 16; i++) v[i] = cmul(v[i], kv[i]);
        dft16<true>(v);
        #pragma unroll
        for (int i = 0; i < 8; i++)
            *(float4*)&z[ZI(c0 + 2 * i)] = make_float4(v[2 * i].x, v[2 * i].y,
                                                       v[2 * i + 1].x, v[2 * i + 1].y);
        __syncthreads();

        stage_inv<16, 64>(z, tw);
        stage_inv<128, 8>(z, tw);

        // last inverse stage (L=1024) fused with epilogue; outputs pos < 4096
        {
            int j0 = 2 * t;
            cf a[8], b[8];
            #pragma unroll
            for (int k = 0; k < 8; k++) {
                float4 p = *(const float4*)&z[ZI(j0 + k * 1024)];
                a[k] = make_float2(p.x, p.y); b[k] = make_float2(p.z, p.w);
            }
            #pragma unroll
            for (int k = 1; k < 8; k++) {
                a[k] = cmulj(a[k], tw[j0 * k]);
                b[k] = cmulj(b[k], tw[(j0 + 1) * k]);
            }
            dft8<true>(a); dft8<true>(b);

            float2* oa2 = (float2*)(out + ((size_t)(2 * pair) * DMODEL + d) * SEQ);
            float2* ob2 = (float2*)(out + ((size_t)(2 * pair + 1) * DMODEL + d) * SEQ);
            #pragma unroll
            for (int m = 0; m < 4; m++) {
                int s = t + 512 * m;
                oa2[s] = make_float2(a[m].x + bd * ra[m].x, b[m].x + bd * ra[m].y);
                ob2[s] = make_float2(a[m].y + bd * rb[m].x, b[m].y + bd * rb[m].y);
            }
        }
    }
}

// ---------------------------------------------------------------------------
extern "C" void kernel_launch(void* const* d_in, const int* in_sizes, int n_in,
                              void* d_out, int out_size, void* d_ws, size_t ws_size,
                              hipStream_t stream) {
    (void)in_sizes; (void)n_in; (void)out_size; (void)ws_size;
    const float* x    = (const float*)d_in[0];
    const float* bias = (const float*)d_in[1];
    const float* W1   = (const float*)d_in[2];
    const float* b1   = (const float*)d_in[3];
    const float* W2   = (const float*)d_in[4];
    const float* b2   = (const float*)d_in[5];
    const float* W3   = (const float*)d_in[6];
    const float* b3   = (const float*)d_in[7];
    const float* Wout = (const float*)d_in[8];
    const float* freq = (const float*)d_in[9];
    float* out = (float*)d_out;

    // ws floats: Ht[262144] | tw[8192 cf] | kfil[4194304]
    float* wsf  = (float*)d_ws;
    float* Ht   = wsf;
    cf*    tw   = (cf*)(wsf + 262144);
    float* kfil = wsf + 262144 + 16384;

    hipLaunchKernelGGL(mlp_kernel, dim3(SEQ / 4), dim3(MLPT), 0, stream,
                       W1, b1, W2, b2, W3, b3, freq, Ht, tw);
    hipLaunchKernelGGL(kgen2_kernel, dim3(1024), dim3(MLPT), 0, stream, Wout, Ht, kfil);
    hipLaunchKernelGGL(conv_kernel, dim3(DMODEL), dim3(CT), 0, stream,
                       x, bias, kfil, tw, out);
}

// Round 10
// 236.796 us; speedup vs baseline: 3.2820x; 3.2820x over previous
//
#include <hip/hip_runtime.h>
#include <math.h>

#define SEQ    4096
#define NFFT   8192
#define DMODEL 1024
#define ORDER  64
#define CT     512
#define MLPT   256

typedef float2 cf;

// LDS swizzle on complex index: XOR bits [3:1] with bits [6:4].
// Preserves even pairs (bit 0) and float4 (16 B) alignment.
#define ZI(c) ((c) ^ ((((c) >> 4) & 7) << 1))

__device__ __forceinline__ cf cadd(cf a, cf b) { return make_float2(a.x + b.x, a.y + b.y); }
__device__ __forceinline__ cf csub(cf a, cf b) { return make_float2(a.x - b.x, a.y - b.y); }
__device__ __forceinline__ cf cmul(cf a, cf b) { return make_float2(a.x * b.x - a.y * b.y, a.x * b.y + a.y * b.x); }
__device__ __forceinline__ cf cmulj(cf a, cf b) { return make_float2(a.x * b.x + a.y * b.y, a.y * b.x - a.x * b.y); } // a*conj(b)

#define RT2 0.70710678118654752f
#define C16 0.92387953251128676f
#define S16 0.38268343236508977f

template<bool INV>
__device__ __forceinline__ cf cmulc(cf a, float cx, float sy) {
    if (!INV) return make_float2(a.x * cx + a.y * sy, a.y * cx - a.x * sy);
    else      return make_float2(a.x * cx - a.y * sy, a.y * cx + a.x * sy);
}
template<bool INV> __device__ __forceinline__ cf tw8_1(cf d) {
    if (!INV) return make_float2(RT2 * (d.x + d.y), RT2 * (d.y - d.x));
    else      return make_float2(RT2 * (d.x - d.y), RT2 * (d.y + d.x));
}
template<bool INV> __device__ __forceinline__ cf tw8_2(cf d) {
    if (!INV) return make_float2(d.y, -d.x);
    else      return make_float2(-d.y, d.x);
}
template<bool INV> __device__ __forceinline__ cf tw8_3(cf d) {
    if (!INV) return make_float2(RT2 * (d.y - d.x), -RT2 * (d.x + d.y));
    else      return make_float2(-RT2 * (d.x + d.y), RT2 * (d.x - d.y));
}

template<bool INV>
__device__ __forceinline__ void dft4(cf& x0, cf& x1, cf& x2, cf& x3) {
    cf A = cadd(x0, x2), B = csub(x0, x2);
    cf C = cadd(x1, x3), D = csub(x1, x3);
    x0 = cadd(A, C); x2 = csub(A, C);
    if (!INV) { x1 = make_float2(B.x + D.y, B.y - D.x); x3 = make_float2(B.x - D.y, B.y + D.x); }
    else      { x1 = make_float2(B.x - D.y, B.y + D.x); x3 = make_float2(B.x + D.y, B.y - D.x); }
}

template<bool INV>
__device__ __forceinline__ void dft8(cf v[8]) {
    cf s0 = cadd(v[0], v[4]), s1 = cadd(v[1], v[5]), s2 = cadd(v[2], v[6]), s3 = cadd(v[3], v[7]);
    cf d0 = csub(v[0], v[4]), d1 = csub(v[1], v[5]), d2 = csub(v[2], v[6]), d3 = csub(v[3], v[7]);
    cf t1 = tw8_1<INV>(d1), t2 = tw8_2<INV>(d2), t3 = tw8_3<INV>(d3);
    dft4<INV>(s0, s1, s2, s3);
    dft4<INV>(d0, t1, t2, t3);
    v[0] = s0; v[2] = s1; v[4] = s2; v[6] = s3;
    v[1] = d0; v[3] = t1; v[5] = t2; v[7] = t3;
}

template<bool INV>
__device__ __forceinline__ void dft16(cf v[16]) {
    cf s[8], t[8];
    #pragma unroll
    for (int m = 0; m < 8; m++) { s[m] = cadd(v[m], v[m + 8]); t[m] = csub(v[m], v[m + 8]); }
    t[1] = cmulc<INV>(t[1], C16, S16);
    t[2] = tw8_1<INV>(t[2]);
    t[3] = cmulc<INV>(t[3], S16, C16);
    t[4] = tw8_2<INV>(t[4]);
    t[5] = cmulc<INV>(t[5], -S16, C16);
    t[6] = tw8_3<INV>(t[6]);
    t[7] = cmulc<INV>(t[7], -C16, S16);
    dft8<INV>(s); dft8<INV>(t);
    #pragma unroll
    for (int k = 0; k < 8; k++) { v[2 * k] = s[k]; v[2 * k + 1] = t[k]; }
}

// Radix-8 stage, pair-of-butterflies per thread (b128 LDS ops).
// Twiddle powers: 2 LUT loads + log-depth chain (dep depth 3).
template<int L, int S, bool FIRST>
__device__ __forceinline__ void stage_fwd(float2* z, const cf* __restrict__ tw) {
    int t = threadIdx.x;
    int j0 = 2 * (t & (L / 2 - 1));
    int base = (t / (L / 2)) * (8 * L);
    int c0 = base + j0;
    cf a[8], b[8];
    #pragma unroll
    for (int k = 0; k < 8; k++) {
        if (FIRST && k >= 4) { a[k] = make_float2(0.f, 0.f); b[k] = a[k]; }
        else {
            float4 p = *(const float4*)&z[ZI(c0 + k * L)];
            a[k] = make_float2(p.x, p.y); b[k] = make_float2(p.z, p.w);
        }
    }
    dft8<false>(a); dft8<false>(b);
    cf wA1 = tw[S * j0],       wB1 = tw[S * j0 + S];
    cf wA2 = cmul(wA1, wA1),   wB2 = cmul(wB1, wB1);
    cf wA3 = cmul(wA2, wA1),   wB3 = cmul(wB2, wB1);
    cf wA4 = cmul(wA2, wA2),   wB4 = cmul(wB2, wB2);
    cf wA5 = cmul(wA3, wA2),   wB5 = cmul(wB3, wB2);
    cf wA6 = cmul(wA3, wA3),   wB6 = cmul(wB3, wB3);
    cf wA7 = cmul(wA4, wA3),   wB7 = cmul(wB4, wB3);
    a[1] = cmul(a[1], wA1); b[1] = cmul(b[1], wB1);
    a[2] = cmul(a[2], wA2); b[2] = cmul(b[2], wB2);
    a[3] = cmul(a[3], wA3); b[3] = cmul(b[3], wB3);
    a[4] = cmul(a[4], wA4); b[4] = cmul(b[4], wB4);
    a[5] = cmul(a[5], wA5); b[5] = cmul(b[5], wB5);
    a[6] = cmul(a[6], wA6); b[6] = cmul(b[6], wB6);
    a[7] = cmul(a[7], wA7); b[7] = cmul(b[7], wB7);
    #pragma unroll
    for (int k = 0; k < 8; k++)
        *(float4*)&z[ZI(c0 + k * L)] = make_float4(a[k].x, a[k].y, b[k].x, b[k].y);
    __syncthreads();
}

template<int L, int S>
__device__ __forceinline__ void stage_inv(float2* z, const cf* __restrict__ tw) {
    int t = threadIdx.x;
    int j0 = 2 * (t & (L / 2 - 1));
    int base = (t / (L / 2)) * (8 * L);
    int c0 = base + j0;
    cf a[8], b[8];
    #pragma unroll
    for (int k = 0; k < 8; k++) {
        float4 p = *(const float4*)&z[ZI(c0 + k * L)];
        a[k] = make_float2(p.x, p.y); b[k] = make_float2(p.z, p.w);
    }
    cf wA1 = tw[S * j0],       wB1 = tw[S * j0 + S];
    cf wA2 = cmul(wA1, wA1),   wB2 = cmul(wB1, wB1);
    cf wA3 = cmul(wA2, wA1),   wB3 = cmul(wB2, wB1);
    cf wA4 = cmul(wA2, wA2),   wB4 = cmul(wB2, wB2);
    cf wA5 = cmul(wA3, wA2),   wB5 = cmul(wB3, wB2);
    cf wA6 = cmul(wA3, wA3),   wB6 = cmul(wB3, wB3);
    cf wA7 = cmul(wA4, wA3),   wB7 = cmul(wB4, wB3);
    a[1] = cmulj(a[1], wA1); b[1] = cmulj(b[1], wB1);
    a[2] = cmulj(a[2], wA2); b[2] = cmulj(b[2], wB2);
    a[3] = cmulj(a[3], wA3); b[3] = cmulj(b[3], wB3);
    a[4] = cmulj(a[4], wA4); b[4] = cmulj(b[4], wB4);
    a[5] = cmulj(a[5], wA5); b[5] = cmulj(b[5], wB5);
    a[6] = cmulj(a[6], wA6); b[6] = cmulj(b[6], wB6);
    a[7] = cmulj(a[7], wA7); b[7] = cmulj(b[7], wB7);
    dft8<true>(a); dft8<true>(b);
    #pragma unroll
    for (int k = 0; k < 8; k++)
        *(float4*)&z[ZI(c0 + k * L)] = make_float4(a[k].x, a[k].y, b[k].x, b[k].y);
    __syncthreads();
}

__device__ __forceinline__ int REV3(int u) { // 9-bit base-8 digit reverse
    return ((u & 7) << 6) | (u & 56) | ((u >> 6) & 7);
}

// ---------------------------------------------------------------------------
// MLP hidden states (Ht[o][l]) + twiddle table init (blocks 0..31).
// ---------------------------------------------------------------------------
__global__ void mlp_kernel(const float* __restrict__ W1, const float* __restrict__ b1,
                           const float* __restrict__ W2, const float* __restrict__ b2,
                           const float* __restrict__ W3, const float* __restrict__ b3,
                           const float* __restrict__ freq, float* __restrict__ Ht,
                           cf* __restrict__ tw) {
    if (blockIdx.x < NFFT / MLPT) {
        int j = blockIdx.x * MLPT + threadIdx.x;
        double ang = (2.0 * M_PI / (double)NFFT) * (double)j;
        tw[j] = make_float2((float)cos(ang), (float)(-sin(ang)));
    }

    int o = threadIdx.x & 63;
    int p = threadIdx.x >> 6;
    int l = blockIdx.x * 4 + p;
    __shared__ float hs[4][ORDER];

    float t   = (float)l / 4095.0f;
    float ang = 1e-4f * (float)(2.0 * M_PI) * (float)l / 4096.0f;
    float z0 = t, z1 = cosf(ang), z2 = -sinf(ang);
    float fo = freq[o];

    float a = z0 * W1[o] + z1 * W1[ORDER + o] + z2 * W1[2 * ORDER + o] + b1[o];
    hs[p][o] = sinf(fo * a);
    __syncthreads();

    a = b2[o];
    #pragma unroll
    for (int i = 0; i < ORDER; i++) a += hs[p][i] * W2[i * ORDER + o];
    float h2 = sinf(fo * a);
    __syncthreads();
    hs[p][o] = h2;
    __syncthreads();

    a = b3[o];
    #pragma unroll
    for (int i = 0; i < ORDER; i++) a += hs[p][i] * W3[i * ORDER + o];
    Ht[o * SEQ + l] = sinf(fo * a);
}

// ---------------------------------------------------------------------------
// kgen2: tiled matmul + modulation: kfil[d][l] = (Ht^T Wout)[l][d] * exp(-t_l*delta_d)
// ---------------------------------------------------------------------------
__global__ __launch_bounds__(MLPT) void kgen2_kernel(const float* __restrict__ Wout,
                                                     const float* __restrict__ Ht,
                                                     float* __restrict__ kfil) {
    __shared__ float Hs[ORDER][68];
    __shared__ float Ws[ORDER][68];
    int t  = threadIdx.x;
    int dt = blockIdx.x & 15, lt = blockIdx.x >> 4;

    #pragma unroll
    for (int r = 0; r < 4; r++) {
        int idx = t + 256 * r;
        int o = idx >> 4, c4 = (idx & 15) * 4;
        *(float4*)&Hs[o][c4] = *(const float4*)&Ht[o * SEQ + lt * 64 + c4];
        *(float4*)&Ws[o][c4] = *(const float4*)&Wout[o * DMODEL + dt * 64 + c4];
    }
    __syncthreads();

    int lq = (t & 15) * 4;
    int dq = (t >> 4) * 4;
    float acc[4][4] = {{0.f}};
    #pragma unroll 8
    for (int o = 0; o < ORDER; o++) {
        float4 h = *(float4*)&Hs[o][lq];
        float4 w = *(float4*)&Ws[o][dq];
        acc[0][0] += w.x * h.x; acc[0][1] += w.x * h.y; acc[0][2] += w.x * h.z; acc[0][3] += w.x * h.w;
        acc[1][0] += w.y * h.x; acc[1][1] += w.y * h.y; acc[1][2] += w.y * h.z; acc[1][3] += w.y * h.w;
        acc[2][0] += w.z * h.x; acc[2][1] += w.z * h.y; acc[2][2] += w.z * h.z; acc[2][3] += w.z * h.w;
        acc[3][0] += w.w * h.x; acc[3][1] += w.w * h.y; acc[3][2] += w.w * h.z; acc[3][3] += w.w * h.w;
    }

    const float MIN_D = -3.0701134573253944f;   // log(.01)/1.5
    const float MAX_D = -15.350567286626971f;   // log(.01)/0.3
    int l0 = lt * 64 + lq;
    #pragma unroll
    for (int di = 0; di < 4; di++) {
        int d = dt * 64 + dq + di;
        float delta = fabsf(MIN_D + (MAX_D - MIN_D) * (float)d / 1023.0f);
        float4 o4;
        o4.x = acc[di][0] * expf(-((float)(l0 + 0) / 4095.0f) * delta);
        o4.y = acc[di][1] * expf(-((float)(l0 + 1) / 4095.0f) * delta);
        o4.z = acc[di][2] * expf(-((float)(l0 + 2) / 4095.0f) * delta);
        o4.w = acc[di][3] * expf(-((float)(l0 + 3) / 4095.0f) * delta);
        *(float4*)&kfil[(size_t)d * SEQ + l0] = o4;
    }
}

// ---------------------------------------------------------------------------
// kfft2: real-packed half-size filter FFT with COALESCED output.
// Pack c[n] = k[2n] + i k[2n+1], 4096-pt FFT (3 chain-twiddle stages +
// final dft8 published to LDS), then per virtual thread tt in [0,512):
// untangle bins F_i = REV3(tt) + 512 i into kv[16] and store contiguously at
// Kbr[d*8192 + 16*tt] (the conv machinery order), scaled by 1/8192.
// ---------------------------------------------------------------------------
__global__ __launch_bounds__(MLPT) void kfft2_kernel(const float* __restrict__ kfil,
                                                     const cf* __restrict__ tw,
                                                     cf* __restrict__ Kbr) {
    int d = blockIdx.x, t = threadIdx.x;
    __shared__ __align__(16) float2 z2[SEQ];   // 4096 complex = 32 KB

    const float4* kf4 = (const float4*)(kfil + (size_t)d * SEQ);
    #pragma unroll
    for (int m = 0; m < 4; m++) {
        int s = t + 256 * m;                  // complex pair (2s, 2s+1) < 2048
        *(float4*)&z2[ZI(2 * s)] = kf4[s];
    }
    __syncthreads();

    stage_fwd<512, 2, true>(z2, tw);          // W_4096 = tw[2j]
    stage_fwd<64, 16, false>(z2, tw);         // W_512  = tw[16j]
    stage_fwd<8, 128, false>(z2, tw);         // W_64   = tw[128j]

    {   // final contiguous dft8 (2 blocks per thread), publish to LDS
        int c0 = 16 * t;
        cf v[16];
        #pragma unroll
        for (int i = 0; i < 8; i++) {
            float4 p = *(const float4*)&z2[ZI(c0 + 2 * i)];
            v[2 * i] = make_float2(p.x, p.y); v[2 * i + 1] = make_float2(p.z, p.w);
        }
        dft8<false>(v); dft8<false>(v + 8);
        #pragma unroll
        for (int i = 0; i < 8; i++)
            *(float4*)&z2[ZI(c0 + 2 * i)] = make_float4(v[2 * i].x, v[2 * i].y,
                                                        v[2 * i + 1].x, v[2 * i + 1].y);
    }
    __syncthreads();

    const float sc = 1.0f / (float)NFFT;
    cf* Kd = Kbr + (size_t)d * NFFT;
    #pragma unroll
    for (int sub = 0; sub < 2; sub++) {
        int tt = t + 256 * sub;               // virtual conv-thread in [0,512)
        int r = REV3(tt);
        cf own[8];
        #pragma unroll
        for (int i = 0; i < 4; i++) {
            float4 p = *(const float4*)&z2[ZI(8 * tt + 2 * i)];
            own[2 * i] = make_float2(p.x, p.y); own[2 * i + 1] = make_float2(p.z, p.w);
        }
        cf kv[16];
        if (r == 0) {                         // tt == 0: self-paired bins 512m
            #pragma unroll
            for (int m = 0; m <= 8; m++) {
                cf Cf = own[m & 7], Cg = own[(8 - m) & 7];
                cf A = make_float2(0.5f * (Cf.x + Cg.x), 0.5f * (Cf.y - Cg.y));
                cf B = make_float2(Cf.x - Cg.x, Cf.y + Cg.y);
                cf W = tw[512 * m];
                cf U = make_float2(0.5f * (W.x * B.x - W.y * B.y),
                                   0.5f * (W.x * B.y + W.y * B.x));
                kv[m & 15] = make_float2(sc * (A.x + U.y), sc * (A.y - U.x));
            }
            #pragma unroll
            for (int i = 9; i < 16; i++)
                kv[i] = make_float2(kv[16 - i].x, -kv[16 - i].y);
        } else {
            int bp = REV3(512 - r);           // partner block index
            cf part[8];
            #pragma unroll
            for (int i = 0; i < 4; i++) {
                float4 p = *(const float4*)&z2[ZI(8 * bp + 2 * i)];
                part[2 * i] = make_float2(p.x, p.y); part[2 * i + 1] = make_float2(p.z, p.w);
            }
            #pragma unroll
            for (int i = 0; i < 8; i++) {     // F = r + 512 i  (< 4096)
                cf Cf = own[i], Cg = part[7 - i];
                cf A = make_float2(0.5f * (Cf.x + Cg.x), 0.5f * (Cf.y - Cg.y));
                cf B = make_float2(Cf.x - Cg.x, Cf.y + Cg.y);
                cf W = tw[r + 512 * i];
                cf U = make_float2(0.5f * (W.x * B.x - W.y * B.y),
                                   0.5f * (W.x * B.y + W.y * B.x));
                kv[i] = make_float2(sc * (A.x + U.y), sc * (A.y - U.x));
            }
            #pragma unroll
            for (int i = 8; i < 16; i++) {    // F >= 4096: K[F] = conj(K[8192-F])
                cf Cf = part[15 - i], Cg = own[i - 8];
                cf A = make_float2(0.5f * (Cf.x + Cg.x), 0.5f * (Cf.y - Cg.y));
                cf B = make_float2(Cf.x - Cg.x, Cf.y + Cg.y);
                cf W = tw[(512 - r) + 512 * (15 - i)];
                cf U = make_float2(0.5f * (W.x * B.x - W.y * B.y),
                                   0.5f * (W.x * B.y + W.y * B.x));
                kv[i] = make_float2(sc * (A.x + U.y), -sc * (A.y - U.x));
            }
        }
        float4* K4 = (float4*)(Kd + 16 * tt);
        #pragma unroll
        for (int i = 0; i < 8; i++)
            K4[i] = make_float4(kv[2 * i].x, kv[2 * i].y, kv[2 * i + 1].x, kv[2 * i + 1].y);
    }
}

// ---------------------------------------------------------------------------
// Main conv (round-6 kernel, unchanged): one WG per (channel, batch-pair).
// ---------------------------------------------------------------------------
__global__ __launch_bounds__(CT, 4) void conv_kernel(const float* __restrict__ x,
                                                     const float* __restrict__ bias,
                                                     const cf* __restrict__ Kbr,
                                                     const cf* __restrict__ tw,
                                                     float* __restrict__ out) {
    int wg = blockIdx.x;
    int d = wg & (DMODEL - 1);
    int pair = wg >> 10;
    int t = threadIdx.x;

    const float2* xa2 = (const float2*)(x + ((size_t)(2 * pair) * DMODEL + d) * SEQ);
    const float2* xb2 = (const float2*)(x + ((size_t)(2 * pair + 1) * DMODEL + d) * SEQ);

    __shared__ __align__(16) float2 z[NFFT];

    float2 ra[4], rb[4];
    #pragma unroll
    for (int m = 0; m < 4; m++) {
        int s = t + 512 * m;
        ra[m] = xa2[s]; rb[m] = xb2[s];
        *(float4*)&z[ZI(2 * s)] = make_float4(ra[m].x, rb[m].x, ra[m].y, rb[m].y);
    }
    __syncthreads();

    stage_fwd<1024, 1, true>(z, tw);
    stage_fwd<128, 8, false>(z, tw);
    stage_fwd<16, 64, false>(z, tw);

    cf v[16];
    int c0 = 16 * t;
    #pragma unroll
    for (int i = 0; i < 8; i++) {
        float4 p = *(const float4*)&z[ZI(c0 + 2 * i)];
        v[2 * i] = make_float2(p.x, p.y); v[2 * i + 1] = make_float2(p.z, p.w);
    }
    dft16<false>(v);
    const float4* K4 = (const float4*)(Kbr + (size_t)d * NFFT + c0);
    #pragma unroll
    for (int i = 0; i < 8; i++) {
        float4 kk = K4[i];
        v[2 * i]     = cmul(v[2 * i],     make_float2(kk.x, kk.y));
        v[2 * i + 1] = cmul(v[2 * i + 1], make_float2(kk.z, kk.w));
    }
    dft16<true>(v);
    #pragma unroll
    for (int i = 0; i < 8; i++)
        *(float4*)&z[ZI(c0 + 2 * i)] = make_float4(v[2 * i].x, v[2 * i].y,
                                                   v[2 * i + 1].x, v[2 * i + 1].y);
    __syncthreads();

    stage_inv<16, 64>(z, tw);
    stage_inv<128, 8>(z, tw);

    {
        int j0 = 2 * t;
        cf a[8], b[8];
        #pragma unroll
        for (int k = 0; k < 8; k++) {
            float4 p = *(const float4*)&z[ZI(j0 + k * 1024)];
            a[k] = make_float2(p.x, p.y); b[k] = make_float2(p.z, p.w);
        }
        cf wA1 = tw[j0],           wB1 = tw[j0 + 1];
        cf wA2 = cmul(wA1, wA1),   wB2 = cmul(wB1, wB1);
        cf wA3 = cmul(wA2, wA1),   wB3 = cmul(wB2, wB1);
        cf wA4 = cmul(wA2, wA2),   wB4 = cmul(wB2, wB2);
        cf wA5 = cmul(wA3, wA2),   wB5 = cmul(wB3, wB2);
        cf wA6 = cmul(wA3, wA3),   wB6 = cmul(wB3, wB3);
        cf wA7 = cmul(wA4, wA3),   wB7 = cmul(wB4, wB3);
        a[1] = cmulj(a[1], wA1); b[1] = cmulj(b[1], wB1);
        a[2] = cmulj(a[2], wA2); b[2] = cmulj(b[2], wB2);
        a[3] = cmulj(a[3], wA3); b[3] = cmulj(b[3], wB3);
        a[4] = cmulj(a[4], wA4); b[4] = cmulj(b[4], wB4);
        a[5] = cmulj(a[5], wA5); b[5] = cmulj(b[5], wB5);
        a[6] = cmulj(a[6], wA6); b[6] = cmulj(b[6], wB6);
        a[7] = cmulj(a[7], wA7); b[7] = cmulj(b[7], wB7);
        dft8<true>(a); dft8<true>(b);

        float bd = bias[d];
        float2* oa2 = (float2*)(out + ((size_t)(2 * pair) * DMODEL + d) * SEQ);
        float2* ob2 = (float2*)(out + ((size_t)(2 * pair + 1) * DMODEL + d) * SEQ);
        #pragma unroll
        for (int m = 0; m < 4; m++) {
            int s = t + 512 * m;
            oa2[s] = make_float2(a[m].x + bd * ra[m].x, b[m].x + bd * ra[m].y);
            ob2[s] = make_float2(a[m].y + bd * rb[m].x, b[m].y + bd * rb[m].y);
        }
    }
}

// ---------------------------------------------------------------------------
extern "C" void kernel_launch(void* const* d_in, const int* in_sizes, int n_in,
                              void* d_out, int out_size, void* d_ws, size_t ws_size,
                              hipStream_t stream) {
    (void)in_sizes; (void)n_in; (void)out_size; (void)ws_size;
    const float* x    = (const float*)d_in[0];
    const float* bias = (const float*)d_in[1];
    const float* W1   = (const float*)d_in[2];
    const float* b1   = (const float*)d_in[3];
    const float* W2   = (const float*)d_in[4];
    const float* b2   = (const float*)d_in[5];
    const float* W3   = (const float*)d_in[6];
    const float* b3   = (const float*)d_in[7];
    const float* Wout = (const float*)d_in[8];
    const float* freq = (const float*)d_in[9];
    float* out = (float*)d_out;

    // ws floats: Ht[262144] | tw[8192 cf] | kfil[4194304] | Kbr[8192*1024 cf]
    float* wsf  = (float*)d_ws;
    float* Ht   = wsf;
    cf*    tw   = (cf*)(wsf + 262144);
    float* kfil = wsf + 262144 + 16384;
    cf*    Kbr  = (cf*)(wsf + 262144 + 16384 + 4194304);

    hipLaunchKernelGGL(mlp_kernel, dim3(SEQ / 4), dim3(MLPT), 0, stream,
                       W1, b1, W2, b2, W3, b3, freq, Ht, tw);
    hipLaunchKernelGGL(kgen2_kernel, dim3(1024), dim3(MLPT), 0, stream, Wout, Ht, kfil);
    hipLaunchKernelGGL(kfft2_kernel, dim3(DMODEL), dim3(MLPT), 0, stream, kfil, tw, Kbr);
    hipLaunchKernelGGL(conv_kernel, dim3(DMODEL * 4), dim3(CT), 0, stream,
                       x, bias, Kbr, tw, out);
}